// Round 23
// baseline (371.337 us; speedup 1.0000x reference)
//
#include <hip/hip_runtime.h>
#include <hip/hip_fp16.h>

typedef _Float16 f16;
typedef _Float16 f16x8 __attribute__((ext_vector_type(8)));
typedef _Float16 f16x4 __attribute__((ext_vector_type(4)));
typedef float f32x4 __attribute__((ext_vector_type(4)));

#define AS1 __attribute__((address_space(1)))
#define AS3 __attribute__((address_space(3)))

__device__ __forceinline__ void g2l16(const void* g, void* l) {
  __builtin_amdgcn_global_load_lds((const AS1 void*)g, (AS3 void*)l, 16, 0, 0);
}

// bijective XCD-chunk swizzle (requires nwg % 8 == 0)
__device__ __forceinline__ void xcd_swz(int& bx, int& by, int& bz) {
  int gx = gridDim.x, gy = gridDim.y;
  int nwg = gx * gy * gridDim.z;
  int lin = (blockIdx.z * gy + blockIdx.y) * gx + blockIdx.x;
  int swz = (lin & 7) * (nwg >> 3) + (lin >> 3);
  bx = swz % gx;
  int t = swz / gx;
  by = t % gy;
  bz = t / gy;
}

// ---- fused input conversion: X = [x_r|x_i] fp16 [16384,512] (blocks 0..8191)
// ----                          Wbig [1536,512] fp16          (blocks 8192..8959)
__global__ __launch_bounds__(256) void build_xw(const float* __restrict__ qr,
                                                const float* __restrict__ qi,
                                                const float* __restrict__ wqr,
                                                const float* __restrict__ wqi,
                                                const float* __restrict__ wkr,
                                                const float* __restrict__ wki,
                                                const float* __restrict__ wvr,
                                                const float* __restrict__ wvi,
                                                f16* __restrict__ X,
                                                f16* __restrict__ W) {
  if (blockIdx.x < 8192) {
    long i = (long)blockIdx.x * 256 + threadIdx.x;
    long e = i * 4;
    int m = (int)(e >> 9);
    int k = (int)(e & 511);
    const float* src = (k < 256) ? (qr + (long)m * 256 + k)
                                 : (qi + (long)m * 256 + (k - 256));
    float4 v = *(const float4*)src;
    f16x4 h = {(f16)v.x, (f16)v.y, (f16)v.z, (f16)v.w};
    *(f16x4*)(X + e) = h;
  } else {
    long i = (long)(blockIdx.x - 8192) * 256 + threadIdx.x;
    long e = i * 4;
    int n = (int)(e >> 9);
    int k = (int)(e & 511);
    int sel = n >> 8;
    int row = n & 255;
    int k2 = k & 255;
    bool hi = (k >= 256);
    const float *Wr, *Wi;
    if ((sel >> 1) == 0)      { Wr = wqr; Wi = wqi; }
    else if ((sel >> 1) == 1) { Wr = wkr; Wi = wki; }
    else                      { Wr = wvr; Wi = wvi; }
    const float* src;
    float sgn = 1.0f;
    if ((sel & 1) == 0) {  // real output: [Wr | -Wi]
      if (!hi) src = Wr + (long)row * 256 + k2;
      else   { src = Wi + (long)row * 256 + k2; sgn = -1.0f; }
    } else {               // imag output: [Wi | Wr]
      if (!hi) src = Wi + (long)row * 256 + k2;
      else     src = Wr + (long)row * 256 + k2;
    }
    float4 v = *(const float4*)src;
    f16x4 h = {(f16)(sgn * v.x), (f16)(sgn * v.y), (f16)(sgn * v.z), (f16)(sgn * v.w)};
    *(f16x4*)(W + e) = h;
  }
}

// ------------- NT GEMM, fp16 A/B, 256x128 tile, BK=64, 512 threads -------------
// MODE 0: projection. Q/K column-blocks (bn<1024) -> P fp16 ldc 1536;
//         V column-blocks (bn>=1024) -> written directly into VT transposed.
// MODE 1: C = f16 scaled scores, ldc 4096 + per-64-col-tile stats [nt][16384]
template <int MODE>
__global__ __launch_bounds__(512, 4) void gemm_nt(const f16* __restrict__ A, int lda, long astr,
                                                  const f16* __restrict__ B, int ldb, long bstr,
                                                  int K, float scale,
                                                  void* __restrict__ C0, long cstr,
                                                  float2* __restrict__ stats,
                                                  f16* __restrict__ VT) {
  __shared__ __align__(16) f16 As[256 * 64];
  __shared__ __align__(16) f16 Bs[128 * 64];
  int bx, by, bz;
  xcd_swz(bx, by, bz);
  const f16* Ab = A + (long)bz * astr;
  const f16* Bb = B + (long)bz * bstr;
  const int tid = threadIdx.x;
  const int wave = tid >> 6, lane = tid & 63;
  const int bm = by * 256, bn = bx * 128;
  const int wm = (wave >> 1) * 64, wn = (wave & 1) * 64;
  const int lr = lane & 15, lg = lane >> 4;

  const int srow = wave * 8 + (lane >> 3);
  const int sk = ((lane & 7) ^ (lane >> 3)) * 8;

  f32x4 acc[4][4] = {};

  for (int kt = 0; kt < K; kt += 64) {
#pragma unroll
    for (int it = 0; it < 4; ++it)
      g2l16(Ab + (long)(bm + srow + it * 64) * lda + kt + sk,
            (char*)As + it * 8192 + wave * 1024);
#pragma unroll
    for (int it = 0; it < 2; ++it)
      g2l16(Bb + (long)(bn + srow + it * 64) * ldb + kt + sk,
            (char*)Bs + it * 8192 + wave * 1024);
    __syncthreads();
#pragma unroll
    for (int kk = 0; kk < 2; ++kk) {
      f16x8 af[4], bf[4];
#pragma unroll
      for (int f = 0; f < 4; ++f) {
        int sw = ((kk * 4 + lg) ^ (lr & 7)) * 8;
        af[f] = *(const f16x8*)(As + (wm + f * 16 + lr) * 64 + sw);
        bf[f] = *(const f16x8*)(Bs + (wn + f * 16 + lr) * 64 + sw);
      }
#pragma unroll
      for (int fm = 0; fm < 4; ++fm)
#pragma unroll
        for (int fn = 0; fn < 4; ++fn)
          acc[fm][fn] = __builtin_amdgcn_mfma_f32_16x16x32_f16(af[fm], bf[fn], acc[fm][fn], 0, 0, 0);
    }
    __syncthreads();
  }

  if (MODE == 0 && bn >= 1024) {
    const int b = bm >> 12;
    const int rbase = (bm & 4095) + wm;
#pragma unroll
    for (int fm = 0; fm < 4; ++fm) {
#pragma unroll
      for (int fn = 0; fn < 4; ++fn) {
        int vcol = bn - 1024 + wn + fn * 16 + lr;
        int vrow = rbase + fm * 16 + lg * 4;
        f16x4 h = {(f16)acc[fm][fn][0], (f16)acc[fm][fn][1],
                   (f16)acc[fm][fn][2], (f16)acc[fm][fn][3]};
        *(f16x4*)(VT + ((long)b * 512 + vcol) * 4096 + vrow) = h;
      }
    }
  } else {
#pragma unroll
    for (int fm = 0; fm < 4; ++fm) {
#pragma unroll
      for (int fn = 0; fn < 4; ++fn) {
#pragma unroll
        for (int r = 0; r < 4; ++r) {
          int row = bm + wm + fm * 16 + lg * 4 + r;
          int col = bn + wn + fn * 16 + lr;
          float v = acc[fm][fn][r];
          if (MODE == 0) {
            ((f16*)C0)[(long)row * 1536 + col] = (f16)v;
          } else {
            ((f16*)C0)[(long)bz * cstr + (long)row * 4096 + col] = (f16)(v * scale);
          }
        }
      }
    }
  }

  if (MODE == 1) {
    const int nt = bx * 2 + (wn >> 6);
#pragma unroll
    for (int fm = 0; fm < 4; ++fm) {
#pragma unroll
      for (int r = 0; r < 4; ++r) {
        float v0 = acc[fm][0][r] * scale, v1 = acc[fm][1][r] * scale;
        float v2 = acc[fm][2][r] * scale, v3 = acc[fm][3][r] * scale;
        float mt = fmaxf(fmaxf(v0, v1), fmaxf(v2, v3));
#pragma unroll
        for (int off = 8; off >= 1; off >>= 1) mt = fmaxf(mt, __shfl_xor(mt, off));
        float lt = __expf(v0 - mt) + __expf(v1 - mt) + __expf(v2 - mt) + __expf(v3 - mt);
#pragma unroll
        for (int off = 8; off >= 1; off >>= 1) lt += __shfl_xor(lt, off);
        if (lr == 0) {
          int row = bm + wm + fm * 16 + lg * 4 + r;
          stats[(long)nt * 16384 + (long)bz * 4096 + row] = make_float2(mt, lt);
        }
      }
    }
  }
}

// --------- merge per-tile stats (layout [nt][16384], coalesced reads) ---------
__global__ __launch_bounds__(256) void merge_stats(const float2* __restrict__ stats,
                                                   float2* __restrict__ ml) {
  long row = (long)blockIdx.x * 256 + threadIdx.x;
  float m = -1e30f;
#pragma unroll 8
  for (int i = 0; i < 64; ++i) m = fmaxf(m, stats[i * 16384 + row].x);
  float l = 0.0f;
#pragma unroll 8
  for (int i = 0; i < 64; ++i) {
    float2 s = stats[i * 16384 + row];
    l += s.y * __expf(s.x - m);
  }
  ml[row] = make_float2(m, l);
}

// ===== pv_fused9: 128q x 256c block, 8 waves 2Mx4N (wave 64x64), BK=64 =====
// ds_read/MFMA ratio 0.75 -> 0.5 (16 reads feed 32 MFMA per wave per tile).
// LDS 96 KB (Ps 2x16K + Bs 2x32K) -> 1 block/CU; counted-vmcnt keeps the only
// hard wait (g2l retire) covered by a full tile of flight. Per thread: 1 score
// row (prow=tid>>2), 16 score cols (pc=tid&3), 2 ds_writes, writer 4 f32x4 stores.
// FIFO vmcnt: writer 6/6/4, non-writer 2/2/0.
__global__ __launch_bounds__(512) void pv_fused9(const float2* __restrict__ ml,
                                                 const f16* __restrict__ S16,
                                                 const f16* __restrict__ VT,
                                                 float* __restrict__ attn,
                                                 float* __restrict__ outR,
                                                 float* __restrict__ outI) {
  __shared__ __align__(16) f16 Ps0[128 * 64];
  __shared__ __align__(16) f16 Ps1[128 * 64];
  __shared__ __align__(16) f16 Bs0[256 * 64];
  __shared__ __align__(16) f16 Bs1[256 * 64];
  // 256 blocks: swz = b*64 + rt*2 + ch ; 32 consecutive works per XCD
  int lin = blockIdx.x;
  int swz = (lin & 7) * 32 + (lin >> 3);
  int b = swz >> 6;
  int rem = swz & 63;
  int rt = rem >> 1, ch = rem & 1;
  const int bm = rt * 128;
  const int c0 = ch * 256;

  const int tid = threadIdx.x;
  const int wave = tid >> 6, lane = tid & 63;
  const int wm2 = (wave >> 2) * 64;   // 0 / 64
  const int wn2 = (wave & 3) * 64;    // 0..192
  const int lr = lane & 15, lg = lane >> 4;

  const int prow = tid >> 2;          // 0..127 (score row)
  const int pc = tid & 3;             // 16-f16 group within 64 cols
  const int vrow = wave * 8 + (lane >> 3);
  const int vsw = ((lane & 7) ^ ((lane >> 3) & 7)) * 8;
  float2 mlv = ml[(long)b * 4096 + bm + prow];
  const float mrow = mlv.x;
  const float invl = 1.0f / mlv.y;

  const f16* Sb = S16 + ((long)(b * 4096 + bm + prow)) * 4096 + pc * 16;
  float* Ab = attn + ((long)(b * 4096 + bm + prow)) * 4096 + pc * 16;
  const f16* Vb = VT + (long)(b * 512 + c0) * 4096;
  const int ps0 = ((pc * 2) ^ (prow & 7)) * 8;       // swizzled 8-f16 slots
  const int ps1 = ((pc * 2 + 1) ^ (prow & 7)) * 8;

  f32x4 acc[4][4] = {};
  f16x8 sa0, sa1, sb0, sb1;

#define PV_G2L(BSBUF, KT)                                                   \
  {                                                                         \
    _Pragma("unroll")                                                       \
    for (int i = 0; i < 4; ++i)                                             \
      g2l16(Vb + (long)(i * 64 + vrow) * 4096 + (KT) + vsw,                 \
            (char*)BSBUF + i * 8192 + wave * 1024);                         \
  }

#define PV_EXP(SC0, SC1, PSBUF, KT, DOST)                                   \
  {                                                                         \
    float p[16];                                                            \
    _Pragma("unroll") for (int j = 0; j < 8; ++j) {                         \
      p[j] = __expf((float)SC0[j] - mrow) * invl;                           \
      p[j + 8] = __expf((float)SC1[j] - mrow) * invl;                       \
    }                                                                       \
    if (DOST) {                                                             \
      _Pragma("unroll") for (int q = 0; q < 4; ++q) {                       \
        float4 w = {p[q * 4], p[q * 4 + 1], p[q * 4 + 2], p[q * 4 + 3]};    \
        *(float4*)(Ab + (KT) + q * 4) = w;                                  \
      }                                                                     \
    }                                                                       \
    f16x8 h0 = {(f16)p[0], (f16)p[1], (f16)p[2], (f16)p[3],                 \
                (f16)p[4], (f16)p[5], (f16)p[6], (f16)p[7]};                \
    f16x8 h1 = {(f16)p[8], (f16)p[9], (f16)p[10], (f16)p[11],               \
                (f16)p[12], (f16)p[13], (f16)p[14], (f16)p[15]};            \
    *(f16x8*)(PSBUF + prow * 64 + ps0) = h0;                                \
    *(f16x8*)(PSBUF + prow * 64 + ps1) = h1;                                \
  }

#define PV_MFMA(PSBUF, BSBUF)                                               \
  {                                                                         \
    __builtin_amdgcn_s_setprio(1);                                          \
    _Pragma("unroll")                                                       \
    for (int kk = 0; kk < 2; ++kk) {                                        \
      int sw = ((kk * 4 + lg) ^ (lr & 7)) * 8;                              \
      f16x8 af[4], bf[4];                                                   \
      _Pragma("unroll")                                                     \
      for (int f = 0; f < 4; ++f) {                                         \
        af[f] = *(const f16x8*)(PSBUF + (wm2 + f * 16 + lr) * 64 + sw);     \
        bf[f] = *(const f16x8*)(BSBUF + (wn2 + f * 16 + lr) * 64 + sw);     \
      }                                                                     \
      _Pragma("unroll")                                                     \
      for (int fm = 0; fm < 4; ++fm)                                        \
        _Pragma("unroll")                                                   \
        for (int fn = 0; fn < 4; ++fn)                                      \
          acc[fm][fn] = __builtin_amdgcn_mfma_f32_16x16x32_f16(             \
              af[fm], bf[fn], acc[fm][fn], 0, 0, 0);                        \
    }                                                                       \
    __builtin_amdgcn_s_setprio(0);                                          \
  }

#define PV_SYNC_(N)                                                         \
  asm volatile("s_waitcnt vmcnt(" #N ")" ::: "memory");                     \
  asm volatile("s_waitcnt lgkmcnt(0)" ::: "memory");                        \
  __builtin_amdgcn_s_barrier();                                             \
  __builtin_amdgcn_sched_barrier(0);
#define PV_SYNC(N) PV_SYNC_(N)

// tile t: g2l V(t+1); scores(t+2)x2; MFMA(t); exp(t+1)+stores(t+1); sync
#define PV_TILE(T, BCUR, BNXT, PCUR, PNXT, SC0, SC1, SL0, SL1, VMN, DOST)   \
  {                                                                         \
    PV_G2L(BNXT, ((T) + 1) * 64)                                            \
    SL0 = *(const f16x8*)(Sb + ((T) + 2) * 64);                             \
    SL1 = *(const f16x8*)(Sb + ((T) + 2) * 64 + 8);                         \
    PV_MFMA(PCUR, BCUR)                                                     \
    PV_EXP(SC0, SC1, PNXT, ((T) + 1) * 64, DOST)                            \
    PV_SYNC(VMN)                                                            \
  }

#define PV_RUN(VMF, VMP, VME, DOST)                                         \
  {                                                                         \
    PV_G2L(Bs0, 0)                                                          \
    sa0 = *(const f16x8*)(Sb + 0);                                          \
    sa1 = *(const f16x8*)(Sb + 8);                                          \
    sb0 = *(const f16x8*)(Sb + 64);                                         \
    sb1 = *(const f16x8*)(Sb + 64 + 8);                                     \
    PV_EXP(sa0, sa1, Ps0, 0, DOST)                                          \
    PV_SYNC(VMP)                                                            \
    for (int t = 0; t < 62; t += 2) {                                       \
      PV_TILE(t, Bs0, Bs1, Ps0, Ps1, sb0, sb1, sa0, sa1, VMF, DOST)         \
      PV_TILE(t + 1, Bs1, Bs0, Ps1, Ps0, sa0, sa1, sb0, sb1, VMF, DOST)     \
    }                                                                       \
    {                                                                       \
      PV_G2L(Bs1, 63 * 64)                                                  \
      PV_MFMA(Ps0, Bs0)                                                     \
      PV_EXP(sb0, sb1, Ps1, 63 * 64, DOST)                                  \
      PV_SYNC(VME)                                                          \
    }                                                                       \
    PV_MFMA(Ps1, Bs1)                                                       \
  }

  if (ch == 0) {
    PV_RUN(6, 6, 4, 1)
  } else {
    PV_RUN(2, 2, 0, 0)
  }

#undef PV_RUN
#undef PV_TILE
#undef PV_SYNC
#undef PV_SYNC_
#undef PV_MFMA
#undef PV_EXP
#undef PV_G2L

  float* outp = ch ? outI : outR;
#pragma unroll
  for (int fm = 0; fm < 4; ++fm)
#pragma unroll
    for (int fn = 0; fn < 4; ++fn)
#pragma unroll
      for (int r = 0; r < 4; ++r) {
        int row = bm + wm2 + fm * 16 + lg * 4 + r;
        int col = wn2 + fn * 16 + lr;
        outp[((long)b * 4096 + row) * 256 + col] = acc[fm][fn][r];
      }
}

extern "C" void kernel_launch(void* const* d_in, const int* in_sizes, int n_in,
                              void* d_out, int out_size, void* d_ws, size_t ws_size,
                              hipStream_t stream) {
  const float* qr  = (const float*)d_in[0];
  const float* qi  = (const float*)d_in[1];
  const float* wqr = (const float*)d_in[2];
  const float* wqi = (const float*)d_in[3];
  const float* wkr = (const float*)d_in[4];
  const float* wki = (const float*)d_in[5];
  const float* wvr = (const float*)d_in[6];
  const float* wvi = (const float*)d_in[7];

  float* outR = (float*)d_out;                       // [4,4096,256]
  float* outI = outR + (size_t)4 * 4096 * 256;       // [4,4096,256]
  float* attn = outI + (size_t)4 * 4096 * 256;       // [4,4096,4096] fp32 normalized

  const size_t offX  = 0;
  const size_t offW  = offX + (size_t)16384 * 512 * 2;      // 16 MB
  const size_t offP  = offW + (size_t)1536 * 512 * 2;       // +1.5 MB
  const size_t offVT = offP + (size_t)16384 * 1536 * 2;     // +48 MB
  const size_t offS  = offVT + (size_t)4 * 512 * 4096 * 2;  // +16 MB

  char* ws = (char*)d_ws;
  f16* X   = (f16*)(ws + offX);
  f16* W   = (f16*)(ws + offW);
  f16* P   = (f16*)(ws + offP);
  f16* VT  = (f16*)(ws + offVT);
  f16* S16 = (f16*)(ws + offS);
  float2* stats = (float2*)X;   // [64][16384] 8 MB, X dead after proj
  float2* ml    = (float2*)W;   // [16384] 128 KB, W dead after proj

  build_xw<<<8960, 256, 0, stream>>>(qr, qi, wqr, wqi, wkr, wki, wvr, wvi, X, W);

  // P (Q/K cols) + VT (V cols, direct transposed) : M=16384, N=1536, K=512
  gemm_nt<0><<<dim3(12, 64, 1), 512, 0, stream>>>(X, 512, 0L, W, 512, 0L, 512, 1.0f,
                                                  (void*)P, 0L, nullptr, VT);

  // raw f16 scaled scores + stats : per batch M=N=4096, K=512
  gemm_nt<1><<<dim3(32, 16, 4), 512, 0, stream>>>(P, 1536, (long)4096 * 1536,
                                                  P + 512, 1536, (long)4096 * 1536,
                                                  512, 0.0625f,
                                                  (void*)S16, (long)4096 * 4096, stats, nullptr);

  merge_stats<<<64, 256, 0, stream>>>(stats, ml);

  // fused normalize + PV, 128q x 256c, 0.5 ds_read/MFMA ratio
  pv_fused9<<<256, 512, 0, stream>>>(ml, S16, VT, attn, outR, outI);
}

// Round 24
// 346.724 us; speedup vs baseline: 1.0710x; 1.0710x over previous
//
#include <hip/hip_runtime.h>
#include <hip/hip_fp16.h>

typedef _Float16 f16;
typedef _Float16 f16x8 __attribute__((ext_vector_type(8)));
typedef _Float16 f16x4 __attribute__((ext_vector_type(4)));
typedef float f32x4 __attribute__((ext_vector_type(4)));

#define AS1 __attribute__((address_space(1)))
#define AS3 __attribute__((address_space(3)))

__device__ __forceinline__ void g2l16(const void* g, void* l) {
  __builtin_amdgcn_global_load_lds((const AS1 void*)g, (AS3 void*)l, 16, 0, 0);
}

// bijective XCD-chunk swizzle (requires nwg % 8 == 0)
__device__ __forceinline__ void xcd_swz(int& bx, int& by, int& bz) {
  int gx = gridDim.x, gy = gridDim.y;
  int nwg = gx * gy * gridDim.z;
  int lin = (blockIdx.z * gy + blockIdx.y) * gx + blockIdx.x;
  int swz = (lin & 7) * (nwg >> 3) + (lin >> 3);
  bx = swz % gx;
  int t = swz / gx;
  by = t % gy;
  bz = t / gy;
}

// ---- fused input conversion: X = [x_r|x_i] fp16 [16384,512] (blocks 0..8191)
// ----                          Wbig [1536,512] fp16          (blocks 8192..8959)
__global__ __launch_bounds__(256) void build_xw(const float* __restrict__ qr,
                                                const float* __restrict__ qi,
                                                const float* __restrict__ wqr,
                                                const float* __restrict__ wqi,
                                                const float* __restrict__ wkr,
                                                const float* __restrict__ wki,
                                                const float* __restrict__ wvr,
                                                const float* __restrict__ wvi,
                                                f16* __restrict__ X,
                                                f16* __restrict__ W) {
  if (blockIdx.x < 8192) {
    long i = (long)blockIdx.x * 256 + threadIdx.x;
    long e = i * 4;
    int m = (int)(e >> 9);
    int k = (int)(e & 511);
    const float* src = (k < 256) ? (qr + (long)m * 256 + k)
                                 : (qi + (long)m * 256 + (k - 256));
    float4 v = *(const float4*)src;
    f16x4 h = {(f16)v.x, (f16)v.y, (f16)v.z, (f16)v.w};
    *(f16x4*)(X + e) = h;
  } else {
    long i = (long)(blockIdx.x - 8192) * 256 + threadIdx.x;
    long e = i * 4;
    int n = (int)(e >> 9);
    int k = (int)(e & 511);
    int sel = n >> 8;
    int row = n & 255;
    int k2 = k & 255;
    bool hi = (k >= 256);
    const float *Wr, *Wi;
    if ((sel >> 1) == 0)      { Wr = wqr; Wi = wqi; }
    else if ((sel >> 1) == 1) { Wr = wkr; Wi = wki; }
    else                      { Wr = wvr; Wi = wvi; }
    const float* src;
    float sgn = 1.0f;
    if ((sel & 1) == 0) {  // real output: [Wr | -Wi]
      if (!hi) src = Wr + (long)row * 256 + k2;
      else   { src = Wi + (long)row * 256 + k2; sgn = -1.0f; }
    } else {               // imag output: [Wi | Wr]
      if (!hi) src = Wi + (long)row * 256 + k2;
      else     src = Wr + (long)row * 256 + k2;
    }
    float4 v = *(const float4*)src;
    f16x4 h = {(f16)(sgn * v.x), (f16)(sgn * v.y), (f16)(sgn * v.z), (f16)(sgn * v.w)};
    *(f16x4*)(W + e) = h;
  }
}

// ------------- NT GEMM, fp16 A/B, 256x128 tile, BK=64, 512 threads -------------
// MODE 0: projection. Q/K column-blocks (bn<1024) -> P fp16 ldc 1536;
//         V column-blocks (bn>=1024) -> written directly into VT transposed.
// MODE 1: C = f16 scaled scores, ldc 4096 + per-64-col-tile stats [nt][16384]
template <int MODE>
__global__ __launch_bounds__(512, 4) void gemm_nt(const f16* __restrict__ A, int lda, long astr,
                                                  const f16* __restrict__ B, int ldb, long bstr,
                                                  int K, float scale,
                                                  void* __restrict__ C0, long cstr,
                                                  float2* __restrict__ stats,
                                                  f16* __restrict__ VT) {
  __shared__ __align__(16) f16 As[256 * 64];
  __shared__ __align__(16) f16 Bs[128 * 64];
  int bx, by, bz;
  xcd_swz(bx, by, bz);
  const f16* Ab = A + (long)bz * astr;
  const f16* Bb = B + (long)bz * bstr;
  const int tid = threadIdx.x;
  const int wave = tid >> 6, lane = tid & 63;
  const int bm = by * 256, bn = bx * 128;
  const int wm = (wave >> 1) * 64, wn = (wave & 1) * 64;
  const int lr = lane & 15, lg = lane >> 4;

  const int srow = wave * 8 + (lane >> 3);
  const int sk = ((lane & 7) ^ (lane >> 3)) * 8;

  f32x4 acc[4][4] = {};

  for (int kt = 0; kt < K; kt += 64) {
#pragma unroll
    for (int it = 0; it < 4; ++it)
      g2l16(Ab + (long)(bm + srow + it * 64) * lda + kt + sk,
            (char*)As + it * 8192 + wave * 1024);
#pragma unroll
    for (int it = 0; it < 2; ++it)
      g2l16(Bb + (long)(bn + srow + it * 64) * ldb + kt + sk,
            (char*)Bs + it * 8192 + wave * 1024);
    __syncthreads();
#pragma unroll
    for (int kk = 0; kk < 2; ++kk) {
      f16x8 af[4], bf[4];
#pragma unroll
      for (int f = 0; f < 4; ++f) {
        int sw = ((kk * 4 + lg) ^ (lr & 7)) * 8;
        af[f] = *(const f16x8*)(As + (wm + f * 16 + lr) * 64 + sw);
        bf[f] = *(const f16x8*)(Bs + (wn + f * 16 + lr) * 64 + sw);
      }
#pragma unroll
      for (int fm = 0; fm < 4; ++fm)
#pragma unroll
        for (int fn = 0; fn < 4; ++fn)
          acc[fm][fn] = __builtin_amdgcn_mfma_f32_16x16x32_f16(af[fm], bf[fn], acc[fm][fn], 0, 0, 0);
    }
    __syncthreads();
  }

  if (MODE == 0 && bn >= 1024) {
    const int b = bm >> 12;
    const int rbase = (bm & 4095) + wm;
#pragma unroll
    for (int fm = 0; fm < 4; ++fm) {
#pragma unroll
      for (int fn = 0; fn < 4; ++fn) {
        int vcol = bn - 1024 + wn + fn * 16 + lr;
        int vrow = rbase + fm * 16 + lg * 4;
        f16x4 h = {(f16)acc[fm][fn][0], (f16)acc[fm][fn][1],
                   (f16)acc[fm][fn][2], (f16)acc[fm][fn][3]};
        *(f16x4*)(VT + ((long)b * 512 + vcol) * 4096 + vrow) = h;
      }
    }
  } else {
#pragma unroll
    for (int fm = 0; fm < 4; ++fm) {
#pragma unroll
      for (int fn = 0; fn < 4; ++fn) {
#pragma unroll
        for (int r = 0; r < 4; ++r) {
          int row = bm + wm + fm * 16 + lg * 4 + r;
          int col = bn + wn + fn * 16 + lr;
          float v = acc[fm][fn][r];
          if (MODE == 0) {
            ((f16*)C0)[(long)row * 1536 + col] = (f16)v;
          } else {
            ((f16*)C0)[(long)bz * cstr + (long)row * 4096 + col] = (f16)(v * scale);
          }
        }
      }
    }
  }

  if (MODE == 1) {
    const int nt = bx * 2 + (wn >> 6);
#pragma unroll
    for (int fm = 0; fm < 4; ++fm) {
#pragma unroll
      for (int r = 0; r < 4; ++r) {
        float v0 = acc[fm][0][r] * scale, v1 = acc[fm][1][r] * scale;
        float v2 = acc[fm][2][r] * scale, v3 = acc[fm][3][r] * scale;
        float mt = fmaxf(fmaxf(v0, v1), fmaxf(v2, v3));
#pragma unroll
        for (int off = 8; off >= 1; off >>= 1) mt = fmaxf(mt, __shfl_xor(mt, off));
        float lt = __expf(v0 - mt) + __expf(v1 - mt) + __expf(v2 - mt) + __expf(v3 - mt);
#pragma unroll
        for (int off = 8; off >= 1; off >>= 1) lt += __shfl_xor(lt, off);
        if (lr == 0) {
          int row = bm + wm + fm * 16 + lg * 4 + r;
          stats[(long)nt * 16384 + (long)bz * 4096 + row] = make_float2(mt, lt);
        }
      }
    }
  }
}

// --------- merge per-tile stats (layout [nt][16384], coalesced reads) ---------
__global__ __launch_bounds__(256) void merge_stats(const float2* __restrict__ stats,
                                                   float2* __restrict__ ml) {
  long row = (long)blockIdx.x * 256 + threadIdx.x;
  float m = -1e30f;
#pragma unroll 8
  for (int i = 0; i < 64; ++i) m = fmaxf(m, stats[i * 16384 + row].x);
  float l = 0.0f;
#pragma unroll 8
  for (int i = 0; i < 64; ++i) {
    float2 s = stats[i * 16384 + row];
    l += s.y * __expf(s.x - m);
  }
  ml[row] = make_float2(m, l);
}

// ===== pv_fused5: 64q x 256c, 80 KB LDS, 2 blocks/CU, counted-vmcnt sync =====
__global__ __launch_bounds__(512, 4) void pv_fused5(const float2* __restrict__ ml,
                                                    const f16* __restrict__ S16,
                                                    const f16* __restrict__ VT,
                                                    float* __restrict__ attn,
                                                    float* __restrict__ outR,
                                                    float* __restrict__ outI) {
  __shared__ __align__(16) f16 Ps0[64 * 64];
  __shared__ __align__(16) f16 Ps1[64 * 64];
  __shared__ __align__(16) f16 Bs0[256 * 64];
  __shared__ __align__(16) f16 Bs1[256 * 64];
  int lin = blockIdx.x;
  int swz = (lin & 7) * 64 + (lin >> 3);
  int b = swz >> 7;
  int rem = swz & 127;
  int rt = rem >> 1, ch = rem & 1;
  const int bm = rt * 64;
  const int c0 = ch * 256;

  const int tid = threadIdx.x;
  const int wave = tid >> 6, lane = tid & 63;
  const int wm2 = (wave >> 2) * 32;
  const int wn2 = (wave & 3) * 64;
  const int lr = lane & 15, lg = lane >> 4;

  const int prow = tid >> 3;
  const int pc8 = tid & 7;
  const int vrow = wave * 8 + (lane >> 3);
  const int vsw = ((lane & 7) ^ ((lane >> 3) & 7)) * 8;
  float2 mlv = ml[(long)b * 4096 + bm + prow];
  const float mrow = mlv.x;
  const float invl = 1.0f / mlv.y;

  const f16* Sb = S16 + ((long)(b * 4096 + bm + prow)) * 4096 + pc8 * 8;
  float* Ab = attn + ((long)(b * 4096 + bm + prow)) * 4096 + pc8 * 8;
  const f16* Vb = VT + (long)(b * 512 + c0) * 4096;
  const int pslot = (pc8 ^ (prow & 7)) * 8;

  f32x4 acc[2][4] = {};
  f16x8 scA, scB;

#define PV_G2L(BSBUF, KT)                                                   \
  {                                                                         \
    _Pragma("unroll")                                                       \
    for (int i = 0; i < 4; ++i)                                             \
      g2l16(Vb + (long)(i * 64 + vrow) * 4096 + (KT) + vsw,                 \
            (char*)BSBUF + i * 8192 + wave * 1024);                         \
  }

#define PV_EXP(SC, PSBUF, KT, DOST)                                         \
  {                                                                         \
    float p[8];                                                             \
    _Pragma("unroll") for (int j = 0; j < 8; ++j)                           \
      p[j] = __expf((float)SC[j] - mrow) * invl;                            \
    if (DOST) {                                                             \
      float4 w0 = {p[0], p[1], p[2], p[3]};                                 \
      float4 w1 = {p[4], p[5], p[6], p[7]};                                 \
      *(float4*)(Ab + (KT)) = w0;                                           \
      *(float4*)(Ab + (KT) + 4) = w1;                                       \
    }                                                                       \
    f16x8 h = {(f16)p[0], (f16)p[1], (f16)p[2], (f16)p[3],                  \
               (f16)p[4], (f16)p[5], (f16)p[6], (f16)p[7]};                 \
    *(f16x8*)(PSBUF + prow * 64 + pslot) = h;                               \
  }

#define PV_MFMA(PSBUF, BSBUF)                                               \
  {                                                                         \
    __builtin_amdgcn_s_setprio(1);                                          \
    _Pragma("unroll")                                                       \
    for (int kk = 0; kk < 2; ++kk) {                                        \
      f16x8 af[2];                                                          \
      _Pragma("unroll")                                                     \
      for (int fm = 0; fm < 2; ++fm)                                        \
        af[fm] = *(const f16x8*)(PSBUF + (wm2 + fm * 16 + lr) * 64 +        \
                                 ((kk * 4 + lg) ^ (lr & 7)) * 8);           \
      f16x8 bf[4];                                                          \
      _Pragma("unroll")                                                     \
      for (int f = 0; f < 4; ++f)                                           \
        bf[f] = *(const f16x8*)(BSBUF + (wn2 + f * 16 + lr) * 64 +          \
                                ((kk * 4 + lg) ^ (lr & 7)) * 8);            \
      _Pragma("unroll")                                                     \
      for (int fm = 0; fm < 2; ++fm)                                        \
        _Pragma("unroll")                                                   \
        for (int f = 0; f < 4; ++f)                                         \
          acc[fm][f] = __builtin_amdgcn_mfma_f32_16x16x32_f16(              \
              af[fm], bf[f], acc[fm][f], 0, 0, 0);                          \
    }                                                                       \
    __builtin_amdgcn_s_setprio(0);                                          \
  }

#define PV_SYNC_(N)                                                         \
  asm volatile("s_waitcnt vmcnt(" #N ")" ::: "memory");                     \
  asm volatile("s_waitcnt lgkmcnt(0)" ::: "memory");                        \
  __builtin_amdgcn_s_barrier();                                             \
  __builtin_amdgcn_sched_barrier(0);
#define PV_SYNC(N) PV_SYNC_(N)

#define PV_TILE(T, BCUR, BNXT, PCUR, PNXT, SCONS, SLOAD, VMN, DOST)         \
  {                                                                         \
    PV_G2L(BNXT, ((T) + 1) * 64)                                            \
    SLOAD = *(const f16x8*)(Sb + ((T) + 2) * 64);                           \
    PV_MFMA(PCUR, BCUR)                                                     \
    PV_EXP(SCONS, PNXT, ((T) + 1) * 64, DOST)                               \
    PV_SYNC(VMN)                                                            \
  }

#define PV_RUN(VMF, VMP, VME, DOST)                                         \
  {                                                                         \
    PV_G2L(Bs0, 0)                                                          \
    scA = *(const f16x8*)(Sb + 0);                                          \
    scB = *(const f16x8*)(Sb + 64);                                         \
    PV_EXP(scA, Ps0, 0, DOST)                                               \
    PV_SYNC(VMP)                                                            \
    for (int t = 0; t < 62; t += 2) {                                       \
      PV_TILE(t, Bs0, Bs1, Ps0, Ps1, scB, scA, VMF, DOST)                   \
      PV_TILE(t + 1, Bs1, Bs0, Ps1, Ps0, scA, scB, VMF, DOST)               \
    }                                                                       \
    {                                                                       \
      PV_G2L(Bs1, 63 * 64)                                                  \
      PV_MFMA(Ps0, Bs0)                                                     \
      PV_EXP(scB, Ps1, 63 * 64, DOST)                                       \
      PV_SYNC(VME)                                                          \
    }                                                                       \
    PV_MFMA(Ps1, Bs1)                                                       \
  }

  if (ch == 0) {
    PV_RUN(3, 3, 2, 1)
  } else {
    PV_RUN(1, 1, 0, 0)
  }

#undef PV_RUN
#undef PV_TILE
#undef PV_SYNC
#undef PV_SYNC_
#undef PV_MFMA
#undef PV_EXP
#undef PV_G2L

  float* outp = ch ? outI : outR;
#pragma unroll
  for (int fm = 0; fm < 2; ++fm)
#pragma unroll
    for (int f = 0; f < 4; ++f)
#pragma unroll
      for (int r = 0; r < 4; ++r) {
        int row = bm + wm2 + fm * 16 + lg * 4 + r;
        int col = wn2 + f * 16 + lr;
        outp[((long)b * 4096 + row) * 256 + col] = acc[fm][f][r];
      }
}

extern "C" void kernel_launch(void* const* d_in, const int* in_sizes, int n_in,
                              void* d_out, int out_size, void* d_ws, size_t ws_size,
                              hipStream_t stream) {
  const float* qr  = (const float*)d_in[0];
  const float* qi  = (const float*)d_in[1];
  const float* wqr = (const float*)d_in[2];
  const float* wqi = (const float*)d_in[3];
  const float* wkr = (const float*)d_in[4];
  const float* wki = (const float*)d_in[5];
  const float* wvr = (const float*)d_in[6];
  const float* wvi = (const float*)d_in[7];

  float* outR = (float*)d_out;                       // [4,4096,256]
  float* outI = outR + (size_t)4 * 4096 * 256;       // [4,4096,256]
  float* attn = outI + (size_t)4 * 4096 * 256;       // [4,4096,4096] fp32 normalized

  const size_t offX  = 0;
  const size_t offW  = offX + (size_t)16384 * 512 * 2;      // 16 MB
  const size_t offP  = offW + (size_t)1536 * 512 * 2;       // +1.5 MB
  const size_t offVT = offP + (size_t)16384 * 1536 * 2;     // +48 MB
  const size_t offS  = offVT + (size_t)4 * 512 * 4096 * 2;  // +16 MB

  char* ws = (char*)d_ws;
  f16* X   = (f16*)(ws + offX);
  f16* W   = (f16*)(ws + offW);
  f16* P   = (f16*)(ws + offP);
  f16* VT  = (f16*)(ws + offVT);
  f16* S16 = (f16*)(ws + offS);
  float2* stats = (float2*)X;   // [64][16384] 8 MB, X dead after proj
  float2* ml    = (float2*)W;   // [16384] 128 KB, W dead after proj

  build_xw<<<8960, 256, 0, stream>>>(qr, qi, wqr, wqi, wkr, wki, wvr, wvi, X, W);

  // P (Q/K cols) + VT (V cols, direct transposed) : M=16384, N=1536, K=512
  gemm_nt<0><<<dim3(12, 64, 1), 512, 0, stream>>>(X, 512, 0L, W, 512, 0L, 512, 1.0f,
                                                  (void*)P, 0L, nullptr, VT);

  // raw f16 scaled scores + stats : per batch M=N=4096, K=512
  gemm_nt<1><<<dim3(32, 16, 4), 512, 0, stream>>>(P, 1536, (long)4096 * 1536,
                                                  P + 512, 1536, (long)4096 * 1536,
                                                  512, 0.0625f,
                                                  (void*)S16, (long)4096 * 4096, stats, nullptr);

  merge_stats<<<64, 256, 0, stream>>>(stats, ml);

  // fused normalize + PV, counted-vmcnt sync
  pv_fused5<<<512, 512, 0, stream>>>(ml, S16, VT, attn, outR, outI);
}

// Round 25
// 338.763 us; speedup vs baseline: 1.0962x; 1.0235x over previous
//
#include <hip/hip_runtime.h>
#include <hip/hip_fp16.h>

typedef _Float16 f16;
typedef _Float16 f16x8 __attribute__((ext_vector_type(8)));
typedef _Float16 f16x4 __attribute__((ext_vector_type(4)));
typedef float f32x4 __attribute__((ext_vector_type(4)));

#define AS1 __attribute__((address_space(1)))
#define AS3 __attribute__((address_space(3)))

__device__ __forceinline__ void g2l16(const void* g, void* l) {
  __builtin_amdgcn_global_load_lds((const AS1 void*)g, (AS3 void*)l, 16, 0, 0);
}

// bijective XCD-chunk swizzle (requires nwg % 8 == 0)
__device__ __forceinline__ void xcd_swz(int& bx, int& by, int& bz) {
  int gx = gridDim.x, gy = gridDim.y;
  int nwg = gx * gy * gridDim.z;
  int lin = (blockIdx.z * gy + blockIdx.y) * gx + blockIdx.x;
  int swz = (lin & 7) * (nwg >> 3) + (lin >> 3);
  bx = swz % gx;
  int t = swz / gx;
  by = t % gy;
  bz = t / gy;
}

// ---- fused input conversion: X = [x_r|x_i] fp16 [16384,512] (blocks 0..8191)
// ----                          Wbig [1536,512] fp16          (blocks 8192..8959)
__global__ __launch_bounds__(256) void build_xw(const float* __restrict__ qr,
                                                const float* __restrict__ qi,
                                                const float* __restrict__ wqr,
                                                const float* __restrict__ wqi,
                                                const float* __restrict__ wkr,
                                                const float* __restrict__ wki,
                                                const float* __restrict__ wvr,
                                                const float* __restrict__ wvi,
                                                f16* __restrict__ X,
                                                f16* __restrict__ W) {
  if (blockIdx.x < 8192) {
    long i = (long)blockIdx.x * 256 + threadIdx.x;
    long e = i * 4;
    int m = (int)(e >> 9);
    int k = (int)(e & 511);
    const float* src = (k < 256) ? (qr + (long)m * 256 + k)
                                 : (qi + (long)m * 256 + (k - 256));
    float4 v = *(const float4*)src;
    f16x4 h = {(f16)v.x, (f16)v.y, (f16)v.z, (f16)v.w};
    *(f16x4*)(X + e) = h;
  } else {
    long i = (long)(blockIdx.x - 8192) * 256 + threadIdx.x;
    long e = i * 4;
    int n = (int)(e >> 9);
    int k = (int)(e & 511);
    int sel = n >> 8;
    int row = n & 255;
    int k2 = k & 255;
    bool hi = (k >= 256);
    const float *Wr, *Wi;
    if ((sel >> 1) == 0)      { Wr = wqr; Wi = wqi; }
    else if ((sel >> 1) == 1) { Wr = wkr; Wi = wki; }
    else                      { Wr = wvr; Wi = wvi; }
    const float* src;
    float sgn = 1.0f;
    if ((sel & 1) == 0) {  // real output: [Wr | -Wi]
      if (!hi) src = Wr + (long)row * 256 + k2;
      else   { src = Wi + (long)row * 256 + k2; sgn = -1.0f; }
    } else {               // imag output: [Wi | Wr]
      if (!hi) src = Wi + (long)row * 256 + k2;
      else     src = Wr + (long)row * 256 + k2;
    }
    float4 v = *(const float4*)src;
    f16x4 h = {(f16)(sgn * v.x), (f16)(sgn * v.y), (f16)(sgn * v.z), (f16)(sgn * v.w)};
    *(f16x4*)(W + e) = h;
  }
}

// ------------- NT GEMM, fp16 A/B, 256x128 tile, BK=64, 512 threads -------------
// MODE 0: projection. Q/K column-blocks (bn<1024) -> P fp16 ldc 1536;
//         V column-blocks (bn>=1024) -> written directly into VT transposed.
// MODE 1: C = f16 scaled scores, ldc 4096 + per-64-col-tile stats [nt][16384]
template <int MODE>
__global__ __launch_bounds__(512, 4) void gemm_nt(const f16* __restrict__ A, int lda, long astr,
                                                  const f16* __restrict__ B, int ldb, long bstr,
                                                  int K, float scale,
                                                  void* __restrict__ C0, long cstr,
                                                  float2* __restrict__ stats,
                                                  f16* __restrict__ VT) {
  __shared__ __align__(16) f16 As[256 * 64];
  __shared__ __align__(16) f16 Bs[128 * 64];
  int bx, by, bz;
  xcd_swz(bx, by, bz);
  const f16* Ab = A + (long)bz * astr;
  const f16* Bb = B + (long)bz * bstr;
  const int tid = threadIdx.x;
  const int wave = tid >> 6, lane = tid & 63;
  const int bm = by * 256, bn = bx * 128;
  const int wm = (wave >> 1) * 64, wn = (wave & 1) * 64;
  const int lr = lane & 15, lg = lane >> 4;

  const int srow = wave * 8 + (lane >> 3);
  const int sk = ((lane & 7) ^ (lane >> 3)) * 8;

  f32x4 acc[4][4] = {};

  for (int kt = 0; kt < K; kt += 64) {
#pragma unroll
    for (int it = 0; it < 4; ++it)
      g2l16(Ab + (long)(bm + srow + it * 64) * lda + kt + sk,
            (char*)As + it * 8192 + wave * 1024);
#pragma unroll
    for (int it = 0; it < 2; ++it)
      g2l16(Bb + (long)(bn + srow + it * 64) * ldb + kt + sk,
            (char*)Bs + it * 8192 + wave * 1024);
    __syncthreads();
#pragma unroll
    for (int kk = 0; kk < 2; ++kk) {
      f16x8 af[4], bf[4];
#pragma unroll
      for (int f = 0; f < 4; ++f) {
        int sw = ((kk * 4 + lg) ^ (lr & 7)) * 8;
        af[f] = *(const f16x8*)(As + (wm + f * 16 + lr) * 64 + sw);
        bf[f] = *(const f16x8*)(Bs + (wn + f * 16 + lr) * 64 + sw);
      }
#pragma unroll
      for (int fm = 0; fm < 4; ++fm)
#pragma unroll
        for (int fn = 0; fn < 4; ++fn)
          acc[fm][fn] = __builtin_amdgcn_mfma_f32_16x16x32_f16(af[fm], bf[fn], acc[fm][fn], 0, 0, 0);
    }
    __syncthreads();
  }

  if (MODE == 0 && bn >= 1024) {
    const int b = bm >> 12;
    const int rbase = (bm & 4095) + wm;
#pragma unroll
    for (int fm = 0; fm < 4; ++fm) {
#pragma unroll
      for (int fn = 0; fn < 4; ++fn) {
        int vcol = bn - 1024 + wn + fn * 16 + lr;
        int vrow = rbase + fm * 16 + lg * 4;
        f16x4 h = {(f16)acc[fm][fn][0], (f16)acc[fm][fn][1],
                   (f16)acc[fm][fn][2], (f16)acc[fm][fn][3]};
        *(f16x4*)(VT + ((long)b * 512 + vcol) * 4096 + vrow) = h;
      }
    }
  } else {
#pragma unroll
    for (int fm = 0; fm < 4; ++fm) {
#pragma unroll
      for (int fn = 0; fn < 4; ++fn) {
#pragma unroll
        for (int r = 0; r < 4; ++r) {
          int row = bm + wm + fm * 16 + lg * 4 + r;
          int col = bn + wn + fn * 16 + lr;
          float v = acc[fm][fn][r];
          if (MODE == 0) {
            ((f16*)C0)[(long)row * 1536 + col] = (f16)v;
          } else {
            ((f16*)C0)[(long)bz * cstr + (long)row * 4096 + col] = (f16)(v * scale);
          }
        }
      }
    }
  }

  if (MODE == 1) {
    const int nt = bx * 2 + (wn >> 6);
#pragma unroll
    for (int fm = 0; fm < 4; ++fm) {
#pragma unroll
      for (int r = 0; r < 4; ++r) {
        float v0 = acc[fm][0][r] * scale, v1 = acc[fm][1][r] * scale;
        float v2 = acc[fm][2][r] * scale, v3 = acc[fm][3][r] * scale;
        float mt = fmaxf(fmaxf(v0, v1), fmaxf(v2, v3));
#pragma unroll
        for (int off = 8; off >= 1; off >>= 1) mt = fmaxf(mt, __shfl_xor(mt, off));
        float lt = __expf(v0 - mt) + __expf(v1 - mt) + __expf(v2 - mt) + __expf(v3 - mt);
#pragma unroll
        for (int off = 8; off >= 1; off >>= 1) lt += __shfl_xor(lt, off);
        if (lr == 0) {
          int row = bm + wm + fm * 16 + lg * 4 + r;
          stats[(long)nt * 16384 + (long)bz * 4096 + row] = make_float2(mt, lt);
        }
      }
    }
  }
}

// --------- merge per-tile stats (layout [nt][16384], coalesced reads) ---------
__global__ __launch_bounds__(256) void merge_stats(const float2* __restrict__ stats,
                                                   float2* __restrict__ ml) {
  long row = (long)blockIdx.x * 256 + threadIdx.x;
  float m = -1e30f;
#pragma unroll 8
  for (int i = 0; i < 64; ++i) m = fmaxf(m, stats[i * 16384 + row].x);
  float l = 0.0f;
#pragma unroll 8
  for (int i = 0; i < 64; ++i) {
    float2 s = stats[i * 16384 + row];
    l += s.y * __expf(s.x - m);
  }
  ml[row] = make_float2(m, l);
}

// ===== pv_fused5: 64q x 256c, 80 KB LDS, 2 blocks/CU, counted-vmcnt sync =====
__global__ __launch_bounds__(512, 4) void pv_fused5(const float2* __restrict__ ml,
                                                    const f16* __restrict__ S16,
                                                    const f16* __restrict__ VT,
                                                    float* __restrict__ attn,
                                                    float* __restrict__ outR,
                                                    float* __restrict__ outI) {
  __shared__ __align__(16) f16 Ps0[64 * 64];
  __shared__ __align__(16) f16 Ps1[64 * 64];
  __shared__ __align__(16) f16 Bs0[256 * 64];
  __shared__ __align__(16) f16 Bs1[256 * 64];
  int lin = blockIdx.x;
  int swz = (lin & 7) * 64 + (lin >> 3);
  int b = swz >> 7;
  int rem = swz & 127;
  int rt = rem >> 1, ch = rem & 1;
  const int bm = rt * 64;
  const int c0 = ch * 256;

  const int tid = threadIdx.x;
  const int wave = tid >> 6, lane = tid & 63;
  const int wm2 = (wave >> 2) * 32;
  const int wn2 = (wave & 3) * 64;
  const int lr = lane & 15, lg = lane >> 4;

  const int prow = tid >> 3;
  const int pc8 = tid & 7;
  const int vrow = wave * 8 + (lane >> 3);
  const int vsw = ((lane & 7) ^ ((lane >> 3) & 7)) * 8;
  float2 mlv = ml[(long)b * 4096 + bm + prow];
  const float mrow = mlv.x;
  const float invl = 1.0f / mlv.y;

  const f16* Sb = S16 + ((long)(b * 4096 + bm + prow)) * 4096 + pc8 * 8;
  float* Ab = attn + ((long)(b * 4096 + bm + prow)) * 4096 + pc8 * 8;
  const f16* Vb = VT + (long)(b * 512 + c0) * 4096;
  const int pslot = (pc8 ^ (prow & 7)) * 8;

  f32x4 acc[2][4] = {};
  f16x8 scA, scB;

#define PV_G2L(BSBUF, KT)                                                   \
  {                                                                         \
    _Pragma("unroll")                                                       \
    for (int i = 0; i < 4; ++i)                                             \
      g2l16(Vb + (long)(i * 64 + vrow) * 4096 + (KT) + vsw,                 \
            (char*)BSBUF + i * 8192 + wave * 1024);                         \
  }

#define PV_EXP(SC, PSBUF, KT, DOST)                                         \
  {                                                                         \
    float p[8];                                                             \
    _Pragma("unroll") for (int j = 0; j < 8; ++j)                           \
      p[j] = __expf((float)SC[j] - mrow) * invl;                            \
    if (DOST) {                                                             \
      float4 w0 = {p[0], p[1], p[2], p[3]};                                 \
      float4 w1 = {p[4], p[5], p[6], p[7]};                                 \
      *(float4*)(Ab + (KT)) = w0;                                           \
      *(float4*)(Ab + (KT) + 4) = w1;                                       \
    }                                                                       \
    f16x8 h = {(f16)p[0], (f16)p[1], (f16)p[2], (f16)p[3],                  \
               (f16)p[4], (f16)p[5], (f16)p[6], (f16)p[7]};                 \
    *(f16x8*)(PSBUF + prow * 64 + pslot) = h;                               \
  }

#define PV_MFMA(PSBUF, BSBUF)                                               \
  {                                                                         \
    __builtin_amdgcn_s_setprio(1);                                          \
    _Pragma("unroll")                                                       \
    for (int kk = 0; kk < 2; ++kk) {                                        \
      f16x8 af[2];                                                          \
      _Pragma("unroll")                                                     \
      for (int fm = 0; fm < 2; ++fm)                                        \
        af[fm] = *(const f16x8*)(PSBUF + (wm2 + fm * 16 + lr) * 64 +        \
                                 ((kk * 4 + lg) ^ (lr & 7)) * 8);           \
      f16x8 bf[4];                                                          \
      _Pragma("unroll")                                                     \
      for (int f = 0; f < 4; ++f)                                           \
        bf[f] = *(const f16x8*)(BSBUF + (wn2 + f * 16 + lr) * 64 +          \
                                ((kk * 4 + lg) ^ (lr & 7)) * 8);            \
      _Pragma("unroll")                                                     \
      for (int fm = 0; fm < 2; ++fm)                                        \
        _Pragma("unroll")                                                   \
        for (int f = 0; f < 4; ++f)                                         \
          acc[fm][f] = __builtin_amdgcn_mfma_f32_16x16x32_f16(              \
              af[fm], bf[f], acc[fm][f], 0, 0, 0);                          \
    }                                                                       \
    __builtin_amdgcn_s_setprio(0);                                          \
  }

#define PV_SYNC_(N)                                                         \
  asm volatile("s_waitcnt vmcnt(" #N ")" ::: "memory");                     \
  asm volatile("s_waitcnt lgkmcnt(0)" ::: "memory");                        \
  __builtin_amdgcn_s_barrier();                                             \
  __builtin_amdgcn_sched_barrier(0);
#define PV_SYNC(N) PV_SYNC_(N)

#define PV_TILE(T, BCUR, BNXT, PCUR, PNXT, SCONS, SLOAD, VMN, DOST)         \
  {                                                                         \
    PV_G2L(BNXT, ((T) + 1) * 64)                                            \
    SLOAD = *(const f16x8*)(Sb + ((T) + 2) * 64);                           \
    PV_MFMA(PCUR, BCUR)                                                     \
    PV_EXP(SCONS, PNXT, ((T) + 1) * 64, DOST)                               \
    PV_SYNC(VMN)                                                            \
  }

#define PV_RUN(VMF, VMP, VME, DOST)                                         \
  {                                                                         \
    PV_G2L(Bs0, 0)                                                          \
    scA = *(const f16x8*)(Sb + 0);                                          \
    scB = *(const f16x8*)(Sb + 64);                                         \
    PV_EXP(scA, Ps0, 0, DOST)                                               \
    PV_SYNC(VMP)                                                            \
    for (int t = 0; t < 62; t += 2) {                                       \
      PV_TILE(t, Bs0, Bs1, Ps0, Ps1, scB, scA, VMF, DOST)                   \
      PV_TILE(t + 1, Bs1, Bs0, Ps1, Ps0, scA, scB, VMF, DOST)               \
    }                                                                       \
    {                                                                       \
      PV_G2L(Bs1, 63 * 64)                                                  \
      PV_MFMA(Ps0, Bs0)                                                     \
      PV_EXP(scB, Ps1, 63 * 64, DOST)                                       \
      PV_SYNC(VME)                                                          \
    }                                                                       \
    PV_MFMA(Ps1, Bs1)                                                       \
  }

  if (ch == 0) {
    PV_RUN(3, 3, 2, 1)
  } else {
    PV_RUN(1, 1, 0, 0)
  }

#undef PV_RUN
#undef PV_TILE
#undef PV_SYNC
#undef PV_SYNC_
#undef PV_MFMA
#undef PV_EXP
#undef PV_G2L

  float* outp = ch ? outI : outR;
#pragma unroll
  for (int fm = 0; fm < 2; ++fm)
#pragma unroll
    for (int f = 0; f < 4; ++f)
#pragma unroll
      for (int r = 0; r < 4; ++r) {
        int row = bm + wm2 + fm * 16 + lg * 4 + r;
        int col = wn2 + f * 16 + lr;
        outp[((long)b * 4096 + row) * 256 + col] = acc[fm][f][r];
      }
}

extern "C" void kernel_launch(void* const* d_in, const int* in_sizes, int n_in,
                              void* d_out, int out_size, void* d_ws, size_t ws_size,
                              hipStream_t stream) {
  const float* qr  = (const float*)d_in[0];
  const float* qi  = (const float*)d_in[1];
  const float* wqr = (const float*)d_in[2];
  const float* wqi = (const float*)d_in[3];
  const float* wkr = (const float*)d_in[4];
  const float* wki = (const float*)d_in[5];
  const float* wvr = (const float*)d_in[6];
  const float* wvi = (const float*)d_in[7];

  float* outR = (float*)d_out;                       // [4,4096,256]
  float* outI = outR + (size_t)4 * 4096 * 256;       // [4,4096,256]
  float* attn = outI + (size_t)4 * 4096 * 256;       // [4,4096,4096] fp32 normalized

  const size_t offX  = 0;
  const size_t offW  = offX + (size_t)16384 * 512 * 2;      // 16 MB
  const size_t offP  = offW + (size_t)1536 * 512 * 2;       // +1.5 MB
  const size_t offVT = offP + (size_t)16384 * 1536 * 2;     // +48 MB
  const size_t offS  = offVT + (size_t)4 * 512 * 4096 * 2;  // +16 MB

  char* ws = (char*)d_ws;
  f16* X   = (f16*)(ws + offX);
  f16* W   = (f16*)(ws + offW);
  f16* P   = (f16*)(ws + offP);
  f16* VT  = (f16*)(ws + offVT);
  f16* S16 = (f16*)(ws + offS);
  float2* stats = (float2*)X;   // [64][16384] 8 MB, X dead after proj
  float2* ml    = (float2*)W;   // [16384] 128 KB, W dead after proj

  build_xw<<<8960, 256, 0, stream>>>(qr, qi, wqr, wqi, wkr, wki, wvr, wvi, X, W);

  // P (Q/K cols) + VT (V cols, direct transposed) : M=16384, N=1536, K=512
  gemm_nt<0><<<dim3(12, 64, 1), 512, 0, stream>>>(X, 512, 0L, W, 512, 0L, 512, 1.0f,
                                                  (void*)P, 0L, nullptr, VT);

  // raw f16 scaled scores + stats : per batch M=N=4096, K=512
  gemm_nt<1><<<dim3(32, 16, 4), 512, 0, stream>>>(P, 1536, (long)4096 * 1536,
                                                  P + 512, 1536, (long)4096 * 1536,
                                                  512, 0.0625f,
                                                  (void*)S16, (long)4096 * 4096, stats, nullptr);

  merge_stats<<<64, 256, 0, stream>>>(stats, ml);

  // fused normalize + PV, counted-vmcnt sync
  pv_fused5<<<512, 512, 0, stream>>>(ml, S16, VT, attn, outR, outI);
}